// Round 1
// baseline (184.507 us; speedup 1.0000x reference)
//
#include <hip/hip_runtime.h>

#define B_SZ 4096
#define N_IN 4096
#define N_CTX 512
#define UNITS 4096
#define RANK 256
#define ZSPLIT 8

typedef __attribute__((ext_vector_type(8))) __bf16 bf16x8;
typedef __attribute__((ext_vector_type(4))) float f32x4;
typedef __attribute__((ext_vector_type(8))) unsigned short ushort8;

__device__ __forceinline__ unsigned short f2bf(float f) {
    unsigned int u = __float_as_uint(f);
    u += 0x7FFFu + ((u >> 16) & 1u);   // RNE
    return (unsigned short)(u >> 16);
}
__device__ __forceinline__ float bf2f(unsigned short h) {
    return __uint_as_float(((unsigned int)h) << 16);
}
__device__ __forceinline__ void gload_lds16(const unsigned short* g, unsigned short* l) {
    __builtin_amdgcn_global_load_lds(
        (const __attribute__((address_space(1))) unsigned int*)g,
        (__attribute__((address_space(3))) unsigned int*)l, 16, 0, 0);
}
__device__ __forceinline__ bf16x8 ldfrag(const unsigned short* p) {
    ushort8 t = *(const ushort8*)p;
    return __builtin_bit_cast(bf16x8, t);
}

// ---- fused prep: U^T (bf16), W^T (bf16), V convert (bf16), one launch ----
__global__ void prep(const float* __restrict__ U, const float* __restrict__ W,
                     const float* __restrict__ V,
                     unsigned short* __restrict__ UT, unsigned short* __restrict__ WT,
                     unsigned short* __restrict__ Vb) {
    __shared__ unsigned short t[64][66];
    int bid = blockIdx.x, tid = threadIdx.x;
    if (bid < 288) {
        const float* src; unsigned short* dst; int R, C, rb, cb;
        if (bid < 256) { src = U; dst = UT; R = N_IN; C = RANK; rb = (bid & 63) * 64; cb = (bid >> 6) * 64; }
        else { int b = bid - 256; src = W; dst = WT; R = N_CTX; C = RANK; rb = (b & 7) * 64; cb = (b >> 3) * 64; }
        int r = tid >> 4, c4 = (tid & 15) * 4;
        for (int i = 0; i < 4; i++) {
            float4 v = *(const float4*)(src + (size_t)(rb + r + i * 16) * C + cb + c4);
            t[r + i * 16][c4 + 0] = f2bf(v.x);
            t[r + i * 16][c4 + 1] = f2bf(v.y);
            t[r + i * 16][c4 + 2] = f2bf(v.z);
            t[r + i * 16][c4 + 3] = f2bf(v.w);
        }
        __syncthreads();
        int c = tid >> 3, r8 = (tid & 7) * 8;
        for (int j = 0; j < 2; j++) {
            int cc = c + j * 32;
            ushort8 o;
            for (int k = 0; k < 8; k++) o[k] = t[r8 + k][cc];
            *(ushort8*)(dst + (size_t)(cb + cc) * R + rb + r8) = o;
        }
    } else {
        size_t base = (size_t)(bid - 288) * 2048 + (size_t)tid * 8;
        float4 a = *(const float4*)(V + base);
        float4 b = *(const float4*)(V + base + 4);
        ushort8 o = { f2bf(a.x), f2bf(a.y), f2bf(a.z), f2bf(a.w),
                      f2bf(b.x), f2bf(b.y), f2bf(b.z), f2bf(b.w) };
        *(ushort8*)(Vb + base) = o;
    }
}

// All GEMM tiles: rows of 64 bf16 = 128B = 8 chunks of 16B.
// LDS slot (row, cs) holds data chunk cs^(row&7)  -> bank-balanced b128 access.

// ---- K1: Schi = S * sigmoid(context@W + B), bf16 out ------------------
// tile 32x64, BK=64, grid (4,128) = 512 blocks, double-buffered, 1 barrier/step
__launch_bounds__(256, 4)
__global__ void k1_chi(const float* __restrict__ ctx, const unsigned short* __restrict__ WT,
                       const float* __restrict__ S, const float* __restrict__ Bb,
                       unsigned short* __restrict__ Schi) {
    __shared__ unsigned short As[2][32 * 64];
    __shared__ unsigned short Bs[2][64 * 64];
    int tid = threadIdx.x, w = tid >> 6, lane = tid & 63;
    int ln15 = lane & 15, quad = lane >> 4;
    int wr = w >> 1, wc = w & 1;
    int tm = blockIdx.y * 32, tn = blockIdx.x * 64;
    f32x4 acc2[2] = {};
    int arow = tid >> 3, acs = tid & 7;                 // A: 1 chunk/thread
    const float* ag = ctx + (size_t)(tm + arow) * N_CTX + acs * 8;
    int aoff = arow * 64 + (acs ^ (arow & 7)) * 8;
    int bl8 = lane >> 3, bcs = lane & 7;
    int bgc = (bcs ^ bl8) * 8;                          // swizzled global chunk for B

#define K1_STAGE_B(buf, k0) do { \
    for (int c = 0; c < 2; c++) { \
        int row = w * 16 + c * 8 + bl8; \
        gload_lds16(WT + (size_t)(tn + row) * N_CTX + (k0) + bgc, &Bs[buf][row * 64 + bcs * 8]); \
    } } while (0)

    // prologue: stage tile 0
    K1_STAGE_B(0, 0);
    {
        float4 v0 = *(const float4*)(ag);
        float4 v1 = *(const float4*)(ag + 4);
        ushort8 a8 = { f2bf(v0.x), f2bf(v0.y), f2bf(v0.z), f2bf(v0.w),
                       f2bf(v1.x), f2bf(v1.y), f2bf(v1.z), f2bf(v1.w) };
        *(ushort8*)&As[0][aoff] = a8;
    }
    __syncthreads();

    int cur = 0;
    for (int kt = 0; kt < 8; kt++) {
        int nxt = cur ^ 1;
        bool pf = (kt < 7);
        float4 v0, v1;
        if (pf) {
            int k0 = (kt + 1) * 64;
            K1_STAGE_B(nxt, k0);
            v0 = *(const float4*)(ag + k0);
            v1 = *(const float4*)(ag + k0 + 4);
        }
        for (int kh = 0; kh < 2; kh++) {
            int ch = kh * 4 + quad;
            bf16x8 af = ldfrag(&As[cur][(wr * 16 + ln15) * 64 + (ch ^ (ln15 & 7)) * 8]);
            for (int j = 0; j < 2; j++) {
                bf16x8 bfr = ldfrag(&Bs[cur][(wc * 32 + j * 16 + ln15) * 64 + (ch ^ (ln15 & 7)) * 8]);
                acc2[j] = __builtin_amdgcn_mfma_f32_16x16x32_bf16(af, bfr, acc2[j], 0, 0, 0);
            }
        }
        if (pf) {
            ushort8 a8 = { f2bf(v0.x), f2bf(v0.y), f2bf(v0.z), f2bf(v0.w),
                           f2bf(v1.x), f2bf(v1.y), f2bf(v1.z), f2bf(v1.w) };
            *(ushort8*)&As[nxt][aoff] = a8;
        }
        __syncthreads();
        cur = nxt;
    }
    for (int j = 0; j < 2; j++) {
        int col = tn + wc * 32 + j * 16 + ln15;
        float sv = S[col], bv = Bb[col];
        for (int r = 0; r < 4; r++) {
            int row = tm + wr * 16 + quad * 4 + r;
            float x = acc2[j][r] + bv;
            float chi = sv / (1.f + __expf(-x));
            Schi[(size_t)row * RANK + col] = f2bf(chi);
        }
    }
#undef K1_STAGE_B
}

// ---- K2: T0p[z] = inputs@U partial (split-K, bf16 partials) -----------
// tile 64x128, BK=64, grid (2, 64, 8) = 1024 blocks, double-buffered, 1 barrier/step
__launch_bounds__(256, 3)
__global__ void k2_t0(const float* __restrict__ X, const unsigned short* __restrict__ UT,
                      unsigned short* __restrict__ T0p) {
    __shared__ unsigned short As[2][64 * 64];
    __shared__ unsigned short Bs[2][128 * 64];
    int tid = threadIdx.x, w = tid >> 6, lane = tid & 63;
    int ln15 = lane & 15, quad = lane >> 4;
    int wr = w >> 1, wc = w & 1;
    int tm = blockIdx.y * 64, tn = blockIdx.x * 128;
    int kbase = blockIdx.z * (N_IN / ZSPLIT);
    f32x4 acc[2][4] = {};
    int arow = tid >> 2, acs0 = tid & 3;                // A: 2 chunks/thread (cs0, cs0+4)
    const float* ag = X + (size_t)(tm + arow) * N_IN + kbase;
    int aoff0 = arow * 64 + ((acs0 + 0) ^ (arow & 7)) * 8;
    int aoff1 = arow * 64 + ((acs0 + 4) ^ (arow & 7)) * 8;
    int bl8 = lane >> 3, bcs = lane & 7;
    int bgc = (bcs ^ bl8) * 8;
    const int NT = (N_IN / ZSPLIT) / 64;                // 8

#define K2_STAGE_B(buf, k0) do { \
    for (int c = 0; c < 4; c++) { \
        int row = w * 32 + c * 8 + bl8; \
        gload_lds16(UT + (size_t)(tn + row) * N_IN + kbase + (k0) + bgc, &Bs[buf][row * 64 + bcs * 8]); \
    } } while (0)

    // prologue
    K2_STAGE_B(0, 0);
    {
        float4 v0 = *(const float4*)(ag + acs0 * 8);
        float4 v1 = *(const float4*)(ag + acs0 * 8 + 4);
        float4 u0 = *(const float4*)(ag + (acs0 + 4) * 8);
        float4 u1 = *(const float4*)(ag + (acs0 + 4) * 8 + 4);
        ushort8 a8 = { f2bf(v0.x), f2bf(v0.y), f2bf(v0.z), f2bf(v0.w),
                       f2bf(v1.x), f2bf(v1.y), f2bf(v1.z), f2bf(v1.w) };
        ushort8 b8 = { f2bf(u0.x), f2bf(u0.y), f2bf(u0.z), f2bf(u0.w),
                       f2bf(u1.x), f2bf(u1.y), f2bf(u1.z), f2bf(u1.w) };
        *(ushort8*)&As[0][aoff0] = a8;
        *(ushort8*)&As[0][aoff1] = b8;
    }
    __syncthreads();

    int cur = 0;
    for (int kt = 0; kt < NT; kt++) {
        int nxt = cur ^ 1;
        bool pf = (kt < NT - 1);
        float4 v0, v1, u0, u1;
        if (pf) {
            int k0 = (kt + 1) * 64;
            K2_STAGE_B(nxt, k0);
            v0 = *(const float4*)(ag + k0 + acs0 * 8);
            v1 = *(const float4*)(ag + k0 + acs0 * 8 + 4);
            u0 = *(const float4*)(ag + k0 + (acs0 + 4) * 8);
            u1 = *(const float4*)(ag + k0 + (acs0 + 4) * 8 + 4);
        }
        __builtin_amdgcn_s_setprio(1);
        for (int kh = 0; kh < 2; kh++) {
            int ch = kh * 4 + quad;
            int sw = (ch ^ (ln15 & 7)) * 8;
            bf16x8 af[2], bfr[4];
            for (int i = 0; i < 2; i++)
                af[i] = ldfrag(&As[cur][(wr * 32 + i * 16 + ln15) * 64 + sw]);
            for (int j = 0; j < 4; j++)
                bfr[j] = ldfrag(&Bs[cur][(wc * 64 + j * 16 + ln15) * 64 + sw]);
            for (int i = 0; i < 2; i++)
                for (int j = 0; j < 4; j++)
                    acc[i][j] = __builtin_amdgcn_mfma_f32_16x16x32_bf16(af[i], bfr[j], acc[i][j], 0, 0, 0);
        }
        __builtin_amdgcn_s_setprio(0);
        if (pf) {
            ushort8 a8 = { f2bf(v0.x), f2bf(v0.y), f2bf(v0.z), f2bf(v0.w),
                           f2bf(v1.x), f2bf(v1.y), f2bf(v1.z), f2bf(v1.w) };
            ushort8 b8 = { f2bf(u0.x), f2bf(u0.y), f2bf(u0.z), f2bf(u0.w),
                           f2bf(u1.x), f2bf(u1.y), f2bf(u1.z), f2bf(u1.w) };
            *(ushort8*)&As[nxt][aoff0] = a8;
            *(ushort8*)&As[nxt][aoff1] = b8;
        }
        __syncthreads();
        cur = nxt;
    }
    unsigned short* P = T0p + (size_t)blockIdx.z * B_SZ * RANK;
    for (int i = 0; i < 2; i++)
        for (int j = 0; j < 4; j++) {
            int col = tn + wc * 64 + j * 16 + ln15;
            for (int r = 0; r < 4; r++) {
                int row = tm + wr * 32 + i * 16 + quad * 4 + r;
                P[(size_t)row * RANK + col] = f2bf(acc[i][j][r]);
            }
        }
#undef K2_STAGE_B
}

// ---- E: T = bf16( (sum_z T0p[z]) * Schi ) ------------------------------
__global__ void e_red(const unsigned short* __restrict__ T0p, const unsigned short* __restrict__ Schi,
                      unsigned short* __restrict__ T) {
    int i = blockIdx.x * 256 + threadIdx.x;   // ushort8 index
    const size_t stride = (size_t)B_SZ * RANK;
    float a[8] = {};
    for (int z = 0; z < ZSPLIT; z++) {
        ushort8 p = *(const ushort8*)(T0p + z * stride + (size_t)i * 8);
        for (int k = 0; k < 8; k++) a[k] += bf2f(p[k]);
    }
    ushort8 s = *(const ushort8*)(Schi + (size_t)i * 8);
    ushort8 o;
    for (int k = 0; k < 8; k++) o[k] = f2bf(a[k] * bf2f(s[k]));
    *(ushort8*)(T + (size_t)i * 8) = o;
}

// ---- K3: out = relu(T @ V^T + 2*bias) ---------------------------------
// tile 64x128 (m x n), BK=64 (4 iters), grid (32, 64) = 2048 blocks, dbuf
__launch_bounds__(256, 3)
__global__ void k3_out(const unsigned short* __restrict__ T, const unsigned short* __restrict__ Vb,
                       const float* __restrict__ bias, float* __restrict__ out) {
    __shared__ unsigned short As[2][64 * 64];
    __shared__ unsigned short Bs[2][128 * 64];
    int tid = threadIdx.x, w = tid >> 6, lane = tid & 63;
    int ln15 = lane & 15, quad = lane >> 4;
    int wr = w >> 1, wc = w & 1;
    int tn = blockIdx.x * 128, tm = blockIdx.y * 64;
    f32x4 acc[2][4] = {};
    int bl8 = lane >> 3, bcs = lane & 7;
    int bgc = (bcs ^ bl8) * 8;

#define K3_STAGE(buf, k0) do { \
    for (int c = 0; c < 2; c++) { \
        int row = w * 16 + c * 8 + bl8; \
        gload_lds16(T + (size_t)(tm + row) * RANK + (k0) + bgc, &As[buf][row * 64 + bcs * 8]); \
    } \
    for (int c = 0; c < 4; c++) { \
        int row = w * 32 + c * 8 + bl8; \
        gload_lds16(Vb + (size_t)(tn + row) * RANK + (k0) + bgc, &Bs[buf][row * 64 + bcs * 8]); \
    } } while (0)

    K3_STAGE(0, 0);
    __syncthreads();

    int cur = 0;
    for (int kt = 0; kt < RANK / 64; kt++) {
        int nxt = cur ^ 1;
        if (kt < RANK / 64 - 1) {
            K3_STAGE(nxt, (kt + 1) * 64);
        }
        __builtin_amdgcn_s_setprio(1);
        for (int kh = 0; kh < 2; kh++) {
            int ch = kh * 4 + quad;
            int sw = (ch ^ (ln15 & 7)) * 8;
            bf16x8 af[2], bfr[4];
            for (int i = 0; i < 2; i++)
                af[i] = ldfrag(&As[cur][(wr * 32 + i * 16 + ln15) * 64 + sw]);
            for (int j = 0; j < 4; j++)
                bfr[j] = ldfrag(&Bs[cur][(wc * 64 + j * 16 + ln15) * 64 + sw]);
            for (int i = 0; i < 2; i++)
                for (int j = 0; j < 4; j++)
                    acc[i][j] = __builtin_amdgcn_mfma_f32_16x16x32_bf16(af[i], bfr[j], acc[i][j], 0, 0, 0);
        }
        __builtin_amdgcn_s_setprio(0);
        __syncthreads();
        cur = nxt;
    }
    for (int j = 0; j < 4; j++) {
        int col = tn + wc * 64 + j * 16 + ln15;
        float bv = 2.f * bias[col];
        for (int i = 0; i < 2; i++)
            for (int r = 0; r < 4; r++) {
                int row = tm + wr * 32 + i * 16 + quad * 4 + r;
                float v = acc[i][j][r] + bv;
                out[(size_t)row * UNITS + col] = fmaxf(v, 0.f);
            }
    }
#undef K3_STAGE
}

extern "C" void kernel_launch(void* const* d_in, const int* in_sizes, int n_in,
                              void* d_out, int out_size, void* d_ws, size_t ws_size,
                              hipStream_t stream) {
    (void)in_sizes; (void)n_in; (void)out_size; (void)ws_size;
    const float* inputs  = (const float*)d_in[0];
    const float* context = (const float*)d_in[1];
    const float* U       = (const float*)d_in[2];
    const float* S       = (const float*)d_in[3];
    const float* V       = (const float*)d_in[4];
    const float* W       = (const float*)d_in[5];
    const float* Bb      = (const float*)d_in[6];
    const float* bias    = (const float*)d_in[7];
    float* out = (float*)d_out;

    char* ws = (char*)d_ws;
    size_t o = 0;
    unsigned short* UT   = (unsigned short*)(ws + o); o += (size_t)RANK * N_IN * 2;
    unsigned short* WT   = (unsigned short*)(ws + o); o += (size_t)RANK * N_CTX * 2;
    unsigned short* Vb   = (unsigned short*)(ws + o); o += (size_t)UNITS * RANK * 2;
    unsigned short* Schi = (unsigned short*)(ws + o); o += (size_t)B_SZ * RANK * 2;
    unsigned short* T    = (unsigned short*)(ws + o); o += (size_t)B_SZ * RANK * 2;
    unsigned short* T0p  = (unsigned short*)(ws + o); o += (size_t)ZSPLIT * B_SZ * RANK * 2;

    prep<<<800, 256, 0, stream>>>(U, W, V, UT, WT, Vb);
    k2_t0<<<dim3(RANK / 128, B_SZ / 64, ZSPLIT), 256, 0, stream>>>(inputs, UT, T0p);
    k1_chi<<<dim3(RANK / 64, B_SZ / 32), 256, 0, stream>>>(context, WT, S, Bb, Schi);
    e_red<<<(B_SZ * RANK) / (256 * 8), 256, 0, stream>>>(T0p, Schi, T);
    k3_out<<<dim3(UNITS / 128, B_SZ / 64), 256, 0, stream>>>(T, Vb, bias, out);
}

// Round 2
// 171.067 us; speedup vs baseline: 1.0786x; 1.0786x over previous
//
#include <hip/hip_runtime.h>

#define B_SZ 4096
#define N_IN 4096
#define N_CTX 512
#define UNITS 4096
#define RANK 256
#define ZSPLIT 8

typedef __attribute__((ext_vector_type(8))) __bf16 bf16x8;
typedef __attribute__((ext_vector_type(4))) float f32x4;
typedef __attribute__((ext_vector_type(8))) unsigned short ushort8;

// RNE f32->bf16 via native cast: compiler emits v_cvt_pk_bf16_f32 (1 op / 2 elems)
__device__ __forceinline__ unsigned short f2bf(float f) {
    __bf16 h = (__bf16)f;
    return __builtin_bit_cast(unsigned short, h);
}
__device__ __forceinline__ float bf2f(unsigned short h) {
    return __uint_as_float(((unsigned int)h) << 16);
}
__device__ __forceinline__ void gload_lds16(const unsigned short* g, unsigned short* l) {
    __builtin_amdgcn_global_load_lds(
        (const __attribute__((address_space(1))) unsigned int*)g,
        (__attribute__((address_space(3))) unsigned int*)l, 16, 0, 0);
}
__device__ __forceinline__ bf16x8 ldfrag(const unsigned short* p) {
    ushort8 t = *(const ushort8*)p;
    return __builtin_bit_cast(bf16x8, t);
}

// ---- fused prep: U^T (bf16), W^T (bf16), V convert (bf16), one launch ----
__global__ void prep(const float* __restrict__ U, const float* __restrict__ W,
                     const float* __restrict__ V,
                     unsigned short* __restrict__ UT, unsigned short* __restrict__ WT,
                     unsigned short* __restrict__ Vb) {
    __shared__ unsigned short t[64][66];
    int bid = blockIdx.x, tid = threadIdx.x;
    if (bid < 288) {
        const float* src; unsigned short* dst; int R, C, rb, cb;
        if (bid < 256) { src = U; dst = UT; R = N_IN; C = RANK; rb = (bid & 63) * 64; cb = (bid >> 6) * 64; }
        else { int b = bid - 256; src = W; dst = WT; R = N_CTX; C = RANK; rb = (b & 7) * 64; cb = (b >> 3) * 64; }
        int r = tid >> 4, c4 = (tid & 15) * 4;
        for (int i = 0; i < 4; i++) {
            float4 v = *(const float4*)(src + (size_t)(rb + r + i * 16) * C + cb + c4);
            t[r + i * 16][c4 + 0] = f2bf(v.x);
            t[r + i * 16][c4 + 1] = f2bf(v.y);
            t[r + i * 16][c4 + 2] = f2bf(v.z);
            t[r + i * 16][c4 + 3] = f2bf(v.w);
        }
        __syncthreads();
        int c = tid >> 3, r8 = (tid & 7) * 8;
        for (int j = 0; j < 2; j++) {
            int cc = c + j * 32;
            ushort8 o;
            for (int k = 0; k < 8; k++) o[k] = t[r8 + k][cc];
            *(ushort8*)(dst + (size_t)(cb + cc) * R + rb + r8) = o;
        }
    } else {
        size_t base = (size_t)(bid - 288) * 2048 + (size_t)tid * 8;
        float4 a = *(const float4*)(V + base);
        float4 b = *(const float4*)(V + base + 4);
        ushort8 o = { f2bf(a.x), f2bf(a.y), f2bf(a.z), f2bf(a.w),
                      f2bf(b.x), f2bf(b.y), f2bf(b.z), f2bf(b.w) };
        *(ushort8*)(Vb + base) = o;
    }
}

// All GEMM tiles: rows of 64 bf16 = 128B = 8 chunks of 16B.
// LDS slot (row, cs) holds data chunk cs^(row&7)  -> bank-balanced b128 access.

// ---- K1: Schi = S * sigmoid(context@W + B), bf16 out ------------------
// tile 32x64, BK=64, grid (4,128) = 512 blocks (round-0 structure)
__launch_bounds__(256, 4)
__global__ void k1_chi(const float* __restrict__ ctx, const unsigned short* __restrict__ WT,
                       const float* __restrict__ S, const float* __restrict__ Bb,
                       unsigned short* __restrict__ Schi) {
    __shared__ unsigned short As[32 * 64];
    __shared__ unsigned short Bs[64 * 64];
    int tid = threadIdx.x, w = tid >> 6, lane = tid & 63;
    int ln15 = lane & 15, quad = lane >> 4;
    int wr = w >> 1, wc = w & 1;
    int tm = blockIdx.y * 32, tn = blockIdx.x * 64;
    f32x4 acc2[2] = {};
    int arow = tid >> 3, acs = tid & 7;                 // A: 1 chunk/thread
    const float* ag = ctx + (size_t)(tm + arow) * N_CTX + acs * 8;
    unsigned short* al = As + arow * 64 + (acs ^ (arow & 7)) * 8;
    int bl8 = lane >> 3, bcs = lane & 7;
    int bgc = (bcs ^ bl8) * 8;                          // swizzled global chunk for B
    for (int kt = 0; kt < 8; kt++) {
        int k0 = kt * 64;
        for (int c = 0; c < 2; c++) {
            int row = w * 16 + c * 8 + bl8;
            gload_lds16(WT + (size_t)(tn + row) * N_CTX + k0 + bgc, Bs + row * 64 + bcs * 8);
        }
        {
            float4 v0 = *(const float4*)(ag + k0);
            float4 v1 = *(const float4*)(ag + k0 + 4);
            ushort8 a8 = { f2bf(v0.x), f2bf(v0.y), f2bf(v0.z), f2bf(v0.w),
                           f2bf(v1.x), f2bf(v1.y), f2bf(v1.z), f2bf(v1.w) };
            *(ushort8*)al = a8;
        }
        __syncthreads();
        for (int kh = 0; kh < 2; kh++) {
            int ch = kh * 4 + quad;
            bf16x8 af = ldfrag(As + (wr * 16 + ln15) * 64 + (ch ^ (ln15 & 7)) * 8);
            for (int j = 0; j < 2; j++) {
                int row = wc * 32 + j * 16 + ln15;
                bf16x8 bfr = ldfrag(Bs + row * 64 + (ch ^ (ln15 & 7)) * 8);
                acc2[j] = __builtin_amdgcn_mfma_f32_16x16x32_bf16(af, bfr, acc2[j], 0, 0, 0);
            }
        }
        __syncthreads();
    }
    for (int j = 0; j < 2; j++) {
        int col = tn + wc * 32 + j * 16 + ln15;
        float sv = S[col], bv = Bb[col];
        for (int r = 0; r < 4; r++) {
            int row = tm + wr * 16 + quad * 4 + r;
            float x = acc2[j][r] + bv;
            float chi = sv / (1.f + __expf(-x));
            Schi[(size_t)row * RANK + col] = f2bf(chi);
        }
    }
}

// ---- K2: T0p[z] = inputs@U partial (split-K, bf16 partials) -----------
// tile 64x256 (full RANK, x-grid 1), BK=64, grid (1, 64, 8) = 512 blocks
// 32 MFMA/wave/step, 16 conv elems/thread/step, single-buffer 40KB LDS
__launch_bounds__(256, 2)
__global__ void k2_t0(const float* __restrict__ X, const unsigned short* __restrict__ UT,
                      unsigned short* __restrict__ T0p) {
    __shared__ unsigned short As[64 * 64];
    __shared__ unsigned short Bs[256 * 64];
    int tid = threadIdx.x, w = tid >> 6, lane = tid & 63;
    int ln15 = lane & 15, quad = lane >> 4;
    int wr = w >> 1, wc = w & 1;
    int tm = blockIdx.y * 64;
    int kbase = blockIdx.z * (N_IN / ZSPLIT);
    f32x4 acc[2][8] = {};
    int arow = tid >> 2, acs0 = (tid & 3) * 2;          // A: 2 chunks/thread (16 f32)
    const float* ag = X + (size_t)(tm + arow) * N_IN + kbase + acs0 * 8;
    unsigned short* al0 = As + arow * 64 + ((acs0 + 0) ^ (arow & 7)) * 8;
    unsigned short* al1 = As + arow * 64 + ((acs0 + 1) ^ (arow & 7)) * 8;
    int bl8 = lane >> 3, bcs = lane & 7;
    int bgc = (bcs ^ bl8) * 8;
    for (int kt = 0; kt < (N_IN / ZSPLIT) / 64; kt++) {
        int k0 = kt * 64;
        for (int c = 0; c < 8; c++) {
            int row = w * 64 + c * 8 + bl8;             // rows 0..255 = full RANK
            gload_lds16(UT + (size_t)row * N_IN + kbase + k0 + bgc, Bs + row * 64 + bcs * 8);
        }
        {
            float4 v0 = *(const float4*)(ag + k0);
            float4 v1 = *(const float4*)(ag + k0 + 4);
            float4 u0 = *(const float4*)(ag + k0 + 8);
            float4 u1 = *(const float4*)(ag + k0 + 12);
            ushort8 a8 = { f2bf(v0.x), f2bf(v0.y), f2bf(v0.z), f2bf(v0.w),
                           f2bf(v1.x), f2bf(v1.y), f2bf(v1.z), f2bf(v1.w) };
            ushort8 b8 = { f2bf(u0.x), f2bf(u0.y), f2bf(u0.z), f2bf(u0.w),
                           f2bf(u1.x), f2bf(u1.y), f2bf(u1.z), f2bf(u1.w) };
            *(ushort8*)al0 = a8;
            *(ushort8*)al1 = b8;
        }
        __syncthreads();
        for (int kh = 0; kh < 2; kh++) {
            int ch = kh * 4 + quad;
            int sw = (ch ^ (ln15 & 7)) * 8;
            bf16x8 af[2], bfr[8];
            for (int i = 0; i < 2; i++)
                af[i] = ldfrag(As + (wr * 32 + i * 16 + ln15) * 64 + sw);
            for (int j = 0; j < 8; j++)
                bfr[j] = ldfrag(Bs + (wc * 128 + j * 16 + ln15) * 64 + sw);
            for (int i = 0; i < 2; i++)
                for (int j = 0; j < 8; j++)
                    acc[i][j] = __builtin_amdgcn_mfma_f32_16x16x32_bf16(af[i], bfr[j], acc[i][j], 0, 0, 0);
        }
        __syncthreads();
    }
    unsigned short* P = T0p + (size_t)blockIdx.z * B_SZ * RANK;
    for (int i = 0; i < 2; i++)
        for (int j = 0; j < 8; j++) {
            int col = wc * 128 + j * 16 + ln15;
            for (int r = 0; r < 4; r++) {
                int row = tm + wr * 32 + i * 16 + quad * 4 + r;
                P[(size_t)row * RANK + col] = f2bf(acc[i][j][r]);
            }
        }
}

// ---- E: T = bf16( (sum_z T0p[z]) * Schi ) ------------------------------
__global__ void e_red(const unsigned short* __restrict__ T0p, const unsigned short* __restrict__ Schi,
                      unsigned short* __restrict__ T) {
    int i = blockIdx.x * 256 + threadIdx.x;   // ushort8 index
    const size_t stride = (size_t)B_SZ * RANK;
    float a[8] = {};
    for (int z = 0; z < ZSPLIT; z++) {
        ushort8 p = *(const ushort8*)(T0p + z * stride + (size_t)i * 8);
        for (int k = 0; k < 8; k++) a[k] += bf2f(p[k]);
    }
    ushort8 s = *(const ushort8*)(Schi + (size_t)i * 8);
    ushort8 o;
    for (int k = 0; k < 8; k++) o[k] = f2bf(a[k] * bf2f(s[k]));
    *(ushort8*)(T + (size_t)i * 8) = o;
}

// ---- K3: out = relu(T @ V^T + 2*bias) ---------------------------------
// tile 128x128 (m x n), BK=64 (4 iters), grid (32, 32) = 1024 blocks
// m97 geometry: 32 MFMA/wave/step, 32KB LDS single-buffer
__launch_bounds__(256, 3)
__global__ void k3_out(const unsigned short* __restrict__ T, const unsigned short* __restrict__ Vb,
                       const float* __restrict__ bias, float* __restrict__ out) {
    __shared__ unsigned short As[128 * 64];
    __shared__ unsigned short Bs[128 * 64];
    int tid = threadIdx.x, w = tid >> 6, lane = tid & 63;
    int ln15 = lane & 15, quad = lane >> 4;
    int wr = w >> 1, wc = w & 1;
    int tn = blockIdx.x * 128, tm = blockIdx.y * 128;
    f32x4 acc[4][4] = {};
    int bl8 = lane >> 3, bcs = lane & 7;
    int bgc = (bcs ^ bl8) * 8;
    for (int kt = 0; kt < RANK / 64; kt++) {
        int k0 = kt * 64;
        for (int c = 0; c < 4; c++) {
            int row = w * 32 + c * 8 + bl8;
            gload_lds16(T + (size_t)(tm + row) * RANK + k0 + bgc, As + row * 64 + bcs * 8);
        }
        for (int c = 0; c < 4; c++) {
            int row = w * 32 + c * 8 + bl8;
            gload_lds16(Vb + (size_t)(tn + row) * RANK + k0 + bgc, Bs + row * 64 + bcs * 8);
        }
        __syncthreads();
        for (int kh = 0; kh < 2; kh++) {
            int ch = kh * 4 + quad;
            int sw = (ch ^ (ln15 & 7)) * 8;
            bf16x8 af[4], bfr[4];
            for (int i = 0; i < 4; i++)
                af[i] = ldfrag(As + (wr * 64 + i * 16 + ln15) * 64 + sw);
            for (int j = 0; j < 4; j++)
                bfr[j] = ldfrag(Bs + (wc * 64 + j * 16 + ln15) * 64 + sw);
            for (int i = 0; i < 4; i++)
                for (int j = 0; j < 4; j++)
                    acc[i][j] = __builtin_amdgcn_mfma_f32_16x16x32_bf16(af[i], bfr[j], acc[i][j], 0, 0, 0);
        }
        __syncthreads();
    }
    for (int j = 0; j < 4; j++) {
        int col = tn + wc * 64 + j * 16 + ln15;
        float bv = 2.f * bias[col];
        for (int i = 0; i < 4; i++)
            for (int r = 0; r < 4; r++) {
                int row = tm + wr * 64 + i * 16 + quad * 4 + r;
                float v = acc[i][j][r] + bv;
                out[(size_t)row * UNITS + col] = fmaxf(v, 0.f);
            }
    }
}

extern "C" void kernel_launch(void* const* d_in, const int* in_sizes, int n_in,
                              void* d_out, int out_size, void* d_ws, size_t ws_size,
                              hipStream_t stream) {
    (void)in_sizes; (void)n_in; (void)out_size; (void)ws_size;
    const float* inputs  = (const float*)d_in[0];
    const float* context = (const float*)d_in[1];
    const float* U       = (const float*)d_in[2];
    const float* S       = (const float*)d_in[3];
    const float* V       = (const float*)d_in[4];
    const float* W       = (const float*)d_in[5];
    const float* Bb      = (const float*)d_in[6];
    const float* bias    = (const float*)d_in[7];
    float* out = (float*)d_out;

    char* ws = (char*)d_ws;
    size_t o = 0;
    unsigned short* UT   = (unsigned short*)(ws + o); o += (size_t)RANK * N_IN * 2;
    unsigned short* WT   = (unsigned short*)(ws + o); o += (size_t)RANK * N_CTX * 2;
    unsigned short* Vb   = (unsigned short*)(ws + o); o += (size_t)UNITS * RANK * 2;
    unsigned short* Schi = (unsigned short*)(ws + o); o += (size_t)B_SZ * RANK * 2;
    unsigned short* T    = (unsigned short*)(ws + o); o += (size_t)B_SZ * RANK * 2;
    unsigned short* T0p  = (unsigned short*)(ws + o); o += (size_t)ZSPLIT * B_SZ * RANK * 2;

    prep<<<800, 256, 0, stream>>>(U, W, V, UT, WT, Vb);
    k2_t0<<<dim3(1, B_SZ / 64, ZSPLIT), 256, 0, stream>>>(inputs, UT, T0p);
    k1_chi<<<dim3(RANK / 64, B_SZ / 32), 256, 0, stream>>>(context, WT, S, Bb, Schi);
    e_red<<<(B_SZ * RANK) / (256 * 8), 256, 0, stream>>>(T0p, Schi, T);
    k3_out<<<dim3(UNITS / 128, B_SZ / 128), 256, 0, stream>>>(T, Vb, bias, out);
}